// Round 1
// baseline (206.997 us; speedup 1.0000x reference)
//
#include <hip/hip_runtime.h>
#include <math.h>

#define N_NODES 50000
#define IN_CH 256
#define N_REL 5
#define N_EDGES 800000
#define N_GLOB 20000   // LAST_GLOBALS - LAST_SENSES
#define N_SENSE 25000
#define N_OUT 45000
#define MAX_MATCH 256  // E[matches]=16 (Poisson); 256 is astronomically safe

// ---------------- workspace layout (floats from base) ----------------
// W      : [0, 327680)              5*256*256
// sums   : [327680, 328960)         5*256 (float atomic accumulators)
// x1     : [328960, 329216)         256
// stats  : [329216, 329220)         {m_g, logZ_g, m_s, logZ_s}
// ints   : starting at float offset 329220:
//   ip[0]              edge match count
//   ip[1..5]           per-relation count (dst==0)
//   ip[8 .. 8+256)     matched src
//   ip[8+256 .. 8+512) matched type
// total ~1.33 MB

__global__ void k_init(float* sums, int* ip) {
    int t = threadIdx.x;
    for (int i = t; i < N_REL * IN_CH; i += 256) sums[i] = 0.f;
    if (t < 8) ip[t] = 0;
}

// W[r] = sum_b comp[r,b] * basis[b]
__global__ void k_W(const float* __restrict__ comp,
                    const float* __restrict__ basis,
                    float* __restrict__ W) {
    int idx = blockIdx.x * 256 + threadIdx.x;   // < 327680
    int r  = idx >> 16;
    int df = idx & 65535;
    float acc = 0.f;
#pragma unroll
    for (int b = 0; b < N_REL; ++b)
        acc += comp[r * N_REL + b] * basis[b * (IN_CH * IN_CH) + df];
    W[idx] = acc;
}

// collect edges with dst == 0
__global__ void k_scan(const int* __restrict__ ei,
                       const int* __restrict__ et,
                       int* __restrict__ ip) {
    int e = blockIdx.x * 256 + threadIdx.x;
    if (e >= N_EDGES) return;
    if (ei[N_EDGES + e] == 0) {          // dst row of edge_index
        int t = et[e];
        int p = atomicAdd(&ip[0], 1);
        if (p < MAX_MATCH) {
            ip[8 + p] = ei[e];           // src
            ip[8 + MAX_MATCH + p] = t;   // type
        }
        atomicAdd(&ip[1 + t], 1);
    }
}

// one block per matched edge: msg = x[src] @ W[r]; sums[r] += msg
__global__ void k_msgs(const float* __restrict__ x,
                       const float* __restrict__ W,
                       const int* __restrict__ ip,
                       float* __restrict__ sums) {
    int j = blockIdx.x;
    int m = ip[0]; if (m > MAX_MATCH) m = MAX_MATCH;
    if (j >= m) return;
    __shared__ float xrow[IN_CH];
    int f = threadIdx.x;
    int s = ip[8 + j];
    int r = ip[8 + MAX_MATCH + j];
    xrow[f] = x[(size_t)s * IN_CH + f];
    __syncthreads();
    float msg = 0.f;
    const float* Wr = W + r * (IN_CH * IN_CH);
#pragma unroll 4
    for (int d = 0; d < IN_CH; ++d) msg += xrow[d] * Wr[d * IN_CH + f];
    atomicAdd(&sums[r * IN_CH + f], msg);
}

// x1 = relu( sum_r sums[r]/max(cnt[r],1) + x[0]@root + bias )
__global__ void k_combine(const float* __restrict__ x,
                          const float* __restrict__ root,
                          const float* __restrict__ bias,
                          const float* __restrict__ sums,
                          const int* __restrict__ ip,
                          float* __restrict__ x1) {
    __shared__ float xrow[IN_CH];
    int f = threadIdx.x;
    xrow[f] = x[f];
    __syncthreads();
    float acc = bias[f];
#pragma unroll 4
    for (int d = 0; d < IN_CH; ++d) acc += xrow[d] * root[d * IN_CH + f];
#pragma unroll
    for (int r = 0; r < N_REL; ++r)
        acc += sums[r * IN_CH + f] / fmaxf((float)ip[1 + r], 1.0f);
    x1[f] = fmaxf(acc, 0.f);
}

// one wave per output row: out[row] = dot(Wrow, x1) + b  (unnormalized logits)
__global__ void k_logits(const float* __restrict__ Wg,
                         const float* __restrict__ bg,
                         const float* __restrict__ Ws,
                         const float* __restrict__ bs,
                         const float* __restrict__ x1,
                         float* __restrict__ out) {
    __shared__ float sx[IN_CH];
    int tid = threadIdx.x;
    sx[tid] = x1[tid];
    __syncthreads();
    int lane = tid & 63;
    int row = blockIdx.x * 4 + (tid >> 6);
    if (row >= N_OUT) return;
    const float4* wr;
    float b;
    if (row < N_GLOB) {
        wr = (const float4*)(Wg + (size_t)row * IN_CH);
        b = bg[row];
    } else {
        int r2 = row - N_GLOB;
        wr = (const float4*)(Ws + (size_t)r2 * IN_CH);
        b = bs[r2];
    }
    float4 w = wr[lane];
    float4 xv = ((const float4*)sx)[lane];
    float s = w.x * xv.x + w.y * xv.y + w.z * xv.z + w.w * xv.w;
#pragma unroll
    for (int off = 32; off > 0; off >>= 1) s += __shfl_down(s, off);
    if (lane == 0) out[row] = s + b;
}

// per-segment max and logZ (2 blocks: seg 0 = global, seg 1 = sense)
__global__ void k_stats(const float* __restrict__ out, float* __restrict__ stats) {
    __shared__ float red[256];
    int seg = blockIdx.x;
    int off = seg ? N_GLOB : 0;
    int len = seg ? N_SENSE : N_GLOB;
    int tid = threadIdx.x;
    float m = -3.4e38f;
    for (int i = tid; i < len; i += 256) m = fmaxf(m, out[off + i]);
    red[tid] = m; __syncthreads();
    for (int s2 = 128; s2 > 0; s2 >>= 1) {
        if (tid < s2) red[tid] = fmaxf(red[tid], red[tid + s2]);
        __syncthreads();
    }
    m = red[0]; __syncthreads();
    float s = 0.f;
    for (int i = tid; i < len; i += 256) s += expf(out[off + i] - m);
    red[tid] = s; __syncthreads();
    for (int s2 = 128; s2 > 0; s2 >>= 1) {
        if (tid < s2) red[tid] += red[tid + s2];
        __syncthreads();
    }
    if (tid == 0) { stats[seg * 2] = m; stats[seg * 2 + 1] = logf(red[0]); }
}

__global__ void k_final(float* __restrict__ out, const float* __restrict__ stats) {
    int i = blockIdx.x * 256 + threadIdx.x;
    if (i >= N_OUT) return;
    int seg = (i >= N_GLOB) ? 1 : 0;
    out[i] = out[i] - stats[seg * 2] - stats[seg * 2 + 1];
}

extern "C" void kernel_launch(void* const* d_in, const int* in_sizes, int n_in,
                              void* d_out, int out_size, void* d_ws, size_t ws_size,
                              hipStream_t stream) {
    const float* x     = (const float*)d_in[0];
    const int*   ei    = (const int*)  d_in[1];
    const int*   et    = (const int*)  d_in[2];
    const float* comp  = (const float*)d_in[3];
    const float* basis = (const float*)d_in[4];
    const float* root  = (const float*)d_in[5];
    const float* bias  = (const float*)d_in[6];
    const float* Wg    = (const float*)d_in[7];
    const float* bg    = (const float*)d_in[8];
    const float* Wsn   = (const float*)d_in[9];
    const float* bs    = (const float*)d_in[10];
    float* out = (float*)d_out;

    float* base  = (float*)d_ws;
    float* W     = base;                              // 327680
    float* sums  = base + 327680;                     // 1280
    float* x1    = base + 328960;                     // 256
    float* stats = base + 329216;                     // 4
    int*   ip    = (int*)(base + 329220);

    k_init   <<<1, 256, 0, stream>>>(sums, ip);
    k_W      <<<(N_REL * IN_CH * IN_CH) / 256, 256, 0, stream>>>(comp, basis, W);
    k_scan   <<<(N_EDGES + 255) / 256, 256, 0, stream>>>(ei, et, ip);
    k_msgs   <<<MAX_MATCH, IN_CH, 0, stream>>>(x, W, ip, sums);
    k_combine<<<1, IN_CH, 0, stream>>>(x, root, bias, sums, ip, x1);
    k_logits <<<(N_OUT + 3) / 4, 256, 0, stream>>>(Wg, bg, Wsn, bs, x1, out);
    k_stats  <<<2, 256, 0, stream>>>(out, stats);
    k_final  <<<(N_OUT + 255) / 256, 256, 0, stream>>>(out, stats);
}

// Round 2
// 158.010 us; speedup vs baseline: 1.3100x; 1.3100x over previous
//
#include <hip/hip_runtime.h>
#include <math.h>

#define N_NODES 50000
#define IN_CH 256
#define N_REL 5
#define N_EDGES 800000
#define N_GLOB 20000   // LAST_GLOBALS - LAST_SENSES
#define N_SENSE 25000
#define N_OUT 45000
#define MAX_MATCH 256  // E[matches]=16; 256 is astronomically safe
#define NBLK_LOGITS (N_OUT / 4)   // 11250, 4 rows per block
#define NBLK_GLOB (N_GLOB / 4)    // 5000 -> segment boundary is block-aligned

// ---------------- workspace layout (floats from base) ----------------
// W      : [0, 327680)        5*256*256
// sums   : [327680, 328960)   5*256 atomic accumulators
// x1     : [328960, 329216)
// stats  : [329216, 329220)   {m_g, logZ_g, m_s, logZ_s}
// ip     : ints at float off 329220 (8 + 2*MAX_MATCH ints)
// pmax   : [330240, 341490)   per-logits-block max
// psum   : [341490, 352740)   per-logits-block sum(exp(.-max))

// W[r] = sum_b comp[r,b]*basis[b]; also zero sums/ip (d_ws is poisoned 0xAA)
__global__ void k_W(const float* __restrict__ comp,
                    const float* __restrict__ basis,
                    float* __restrict__ W,
                    float* __restrict__ sums,
                    int* __restrict__ ip) {
    int t = threadIdx.x, bid = blockIdx.x;
    if (bid == 0 && t < 8) ip[t] = 0;
    if (bid < 5) sums[bid * 256 + t] = 0.f;
    int idx = bid * 256 + t;               // < 327680
    int r = idx >> 16, df = idx & 65535;
    float acc = 0.f;
#pragma unroll
    for (int b = 0; b < N_REL; ++b)
        acc += comp[r * N_REL + b] * basis[b * (IN_CH * IN_CH) + df];
    W[idx] = acc;
}

__device__ __forceinline__ void record_edge(const int* ei, const int* et,
                                            int* ip, int e) {
    int t = et[e];
    int p = atomicAdd(&ip[0], 1);
    if (p < MAX_MATCH) {
        ip[8 + p] = ei[e];               // src
        ip[8 + MAX_MATCH + p] = t;       // type
    }
    atomicAdd(&ip[1 + t], 1);
}

// collect edges with dst == 0 (int4-vectorized dst scan)
__global__ void k_scan(const int* __restrict__ ei,
                       const int* __restrict__ et,
                       int* __restrict__ ip) {
    int e4 = blockIdx.x * 256 + threadIdx.x;
    if (e4 * 4 >= N_EDGES) return;
    int4 d = ((const int4*)(ei + N_EDGES))[e4];
    int e = e4 * 4;
    if (d.x == 0) record_edge(ei, et, ip, e);
    if (d.y == 0) record_edge(ei, et, ip, e + 1);
    if (d.z == 0) record_edge(ei, et, ip, e + 2);
    if (d.w == 0) record_edge(ei, et, ip, e + 3);
}

// one block per matched edge, 1024 thr (4-way K-split): sums[r] += x[src]@W[r]
__global__ __launch_bounds__(1024) void k_msgs(const float* __restrict__ x,
                                               const float* __restrict__ W,
                                               const int* __restrict__ ip,
                                               float* __restrict__ sums) {
    int j = blockIdx.x;
    int m = ip[0]; if (m > MAX_MATCH) m = MAX_MATCH;
    if (j >= m) return;
    __shared__ float xrow[IN_CH];
    __shared__ float red[4][IN_CH];
    int tid = threadIdx.x;
    int f = tid & 255, c = tid >> 8;
    int s = ip[8 + j];
    int r = ip[8 + MAX_MATCH + j];
    if (c == 0) xrow[f] = x[(size_t)s * IN_CH + f];
    __syncthreads();
    const float* Wr = W + r * (IN_CH * IN_CH) + c * 64 * IN_CH;
    float acc = 0.f;
#pragma unroll 8
    for (int d = 0; d < 64; ++d) acc += xrow[c * 64 + d] * Wr[d * IN_CH + f];
    red[c][f] = acc;
    __syncthreads();
    if (c == 0)
        atomicAdd(&sums[r * IN_CH + f],
                  red[0][f] + red[1][f] + red[2][f] + red[3][f]);
}

// x1 = relu( sum_r sums[r]/max(cnt,1) + x[0]@root + bias ), 4-way K-split
__global__ __launch_bounds__(1024) void k_combine(const float* __restrict__ x,
                                                  const float* __restrict__ root,
                                                  const float* __restrict__ bias,
                                                  const float* __restrict__ sums,
                                                  const int* __restrict__ ip,
                                                  float* __restrict__ x1) {
    __shared__ float xrow[IN_CH];
    __shared__ float red[4][IN_CH];
    int tid = threadIdx.x;
    int f = tid & 255, c = tid >> 8;
    if (c == 0) xrow[f] = x[f];
    __syncthreads();
    const float* Rr = root + c * 64 * IN_CH;
    float acc = 0.f;
#pragma unroll 8
    for (int d = 0; d < 64; ++d) acc += xrow[c * 64 + d] * Rr[d * IN_CH + f];
    red[c][f] = acc;
    __syncthreads();
    if (c == 0) {
        float a = bias[f] + red[0][f] + red[1][f] + red[2][f] + red[3][f];
#pragma unroll
        for (int r = 0; r < N_REL; ++r)
            a += sums[r * IN_CH + f] / fmaxf((float)ip[1 + r], 1.0f);
        x1[f] = fmaxf(a, 0.f);
    }
}

// 4 rows per block (1 wave each); fused per-block (max, sumexp) partials
__global__ void k_logits(const float* __restrict__ Wg,
                         const float* __restrict__ bg,
                         const float* __restrict__ Ws,
                         const float* __restrict__ bs,
                         const float* __restrict__ x1,
                         float* __restrict__ out,
                         float* __restrict__ pmax,
                         float* __restrict__ psum) {
    __shared__ float sx[IN_CH];
    __shared__ float sl[4];
    int tid = threadIdx.x;
    sx[tid] = x1[tid];
    __syncthreads();
    int lane = tid & 63, w = tid >> 6;
    int row = blockIdx.x * 4 + w;          // N_OUT = 4*11250, no guard needed
    const float4* wr;
    float b;
    if (row < N_GLOB) {
        wr = (const float4*)(Wg + (size_t)row * IN_CH);
        b = bg[row];
    } else {
        int r2 = row - N_GLOB;
        wr = (const float4*)(Ws + (size_t)r2 * IN_CH);
        b = bs[r2];
    }
    float4 wv = wr[lane];
    float4 xv = ((const float4*)sx)[lane];
    float s = wv.x * xv.x + wv.y * xv.y + wv.z * xv.z + wv.w * xv.w;
#pragma unroll
    for (int off = 32; off > 0; off >>= 1) s += __shfl_down(s, off);
    if (lane == 0) { float l = s + b; out[row] = l; sl[w] = l; }
    __syncthreads();
    if (tid == 0) {
        float m4 = fmaxf(fmaxf(sl[0], sl[1]), fmaxf(sl[2], sl[3]));
        float s4 = expf(sl[0] - m4) + expf(sl[1] - m4) +
                   expf(sl[2] - m4) + expf(sl[3] - m4);
        pmax[blockIdx.x] = m4;
        psum[blockIdx.x] = s4;
    }
}

// merge per-block partials with streaming log-sum-exp (1 block per segment)
__global__ void k_stats(const float* __restrict__ pmax,
                        const float* __restrict__ psum,
                        float* __restrict__ stats) {
    __shared__ float rm[256], rs[256];
    int seg = blockIdx.x;
    int off = seg ? NBLK_GLOB : 0;
    int n = seg ? (NBLK_LOGITS - NBLK_GLOB) : NBLK_GLOB;
    int tid = threadIdx.x;
    float m = -3.4e38f, s = 0.f;
    for (int i = tid; i < n; i += 256) {
        float mi = pmax[off + i], si = psum[off + i];
        float M = fmaxf(m, mi);
        s = s * expf(m - M) + si * expf(mi - M);
        m = M;
    }
    rm[tid] = m; rs[tid] = s; __syncthreads();
    for (int h = 128; h > 0; h >>= 1) {
        if (tid < h) {
            float m2 = rm[tid + h], s2 = rs[tid + h];
            float M = fmaxf(rm[tid], m2);
            rs[tid] = rs[tid] * expf(rm[tid] - M) + s2 * expf(m2 - M);
            rm[tid] = M;
        }
        __syncthreads();
    }
    if (tid == 0) { stats[seg * 2] = rm[0]; stats[seg * 2 + 1] = logf(rs[0]); }
}

__global__ void k_final(float* __restrict__ out, const float* __restrict__ stats) {
    int i = blockIdx.x * 256 + threadIdx.x;
    if (i >= N_OUT) return;
    int seg = (i >= N_GLOB) ? 1 : 0;
    out[i] = out[i] - stats[seg * 2] - stats[seg * 2 + 1];
}

extern "C" void kernel_launch(void* const* d_in, const int* in_sizes, int n_in,
                              void* d_out, int out_size, void* d_ws, size_t ws_size,
                              hipStream_t stream) {
    const float* x     = (const float*)d_in[0];
    const int*   ei    = (const int*)  d_in[1];
    const int*   et    = (const int*)  d_in[2];
    const float* comp  = (const float*)d_in[3];
    const float* basis = (const float*)d_in[4];
    const float* root  = (const float*)d_in[5];
    const float* bias  = (const float*)d_in[6];
    const float* Wg    = (const float*)d_in[7];
    const float* bg    = (const float*)d_in[8];
    const float* Wsn   = (const float*)d_in[9];
    const float* bs    = (const float*)d_in[10];
    float* out = (float*)d_out;

    float* base  = (float*)d_ws;
    float* W     = base;
    float* sums  = base + 327680;
    float* x1    = base + 328960;
    float* stats = base + 329216;
    int*   ip    = (int*)(base + 329220);
    float* pmax  = base + 330240;
    float* psum  = base + 341490;

    k_W      <<<(N_REL * IN_CH * IN_CH) / 256, 256, 0, stream>>>(comp, basis, W, sums, ip);
    k_scan   <<<(N_EDGES / 4 + 255) / 256, 256, 0, stream>>>(ei, et, ip);
    k_msgs   <<<MAX_MATCH, 1024, 0, stream>>>(x, W, ip, sums);
    k_combine<<<1, 1024, 0, stream>>>(x, root, bias, sums, ip, x1);
    k_logits <<<NBLK_LOGITS, 256, 0, stream>>>(Wg, bg, Wsn, bs, x1, out, pmax, psum);
    k_stats  <<<2, 256, 0, stream>>>(pmax, psum, stats);
    k_final  <<<(N_OUT + 255) / 256, 256, 0, stream>>>(out, stats);
}